// Round 1
// baseline (288.186 us; speedup 1.0000x reference)
//
#include <hip/hip_runtime.h>
#include <hip/hip_bf16.h>
#include <stdint.h>

typedef unsigned short u16;
typedef unsigned int u32;
using bf16x8 = __attribute__((ext_vector_type(8))) __bf16;
using f32x4  = __attribute__((ext_vector_type(4))) float;

static constexpr int B_ = 4, H_ = 8, S_ = 2048, D_ = 64, DM_ = 512;
#define NEG_INF_F (-1000000000.0f)

__device__ __forceinline__ u16 f2b(float f) {
  u32 u = __float_as_uint(f);
  u = (u + 0x7FFFu + ((u >> 16) & 1u)) >> 16;
  return (u16)u;
}

// ---------------- cast fp32 -> bf16 (vectorized) ----------------
__global__ void cast_f32_bf16_kernel(const float* __restrict__ in, u16* __restrict__ out, int n4) {
  int i = blockIdx.x * blockDim.x + threadIdx.x;
  if (i >= n4) return;
  float4 v = reinterpret_cast<const float4*>(in)[i];
  ushort4 o;
  o.x = f2b(v.x); o.y = f2b(v.y); o.z = f2b(v.z); o.w = f2b(v.w);
  reinterpret_cast<ushort4*>(out)[i] = o;
}

// ---------------- W (K x N) -> Wt bf16 (N x K) ----------------
__global__ void transpose_cast_w_kernel(const float* __restrict__ W, u16* __restrict__ Wt) {
  int i = blockIdx.x * blockDim.x + threadIdx.x; // over 512*512 outputs, n-major
  int n = i >> 9, k = i & 511;
  Wt[i] = f2b(W[k * DM_ + n]);
}

// ---------------- mask int32 -> bitmask ----------------
__global__ void pack_mask_kernel(const int* __restrict__ mask, u32* __restrict__ bits) {
  int i = blockIdx.x * blockDim.x + threadIdx.x;
  unsigned long long bal = __ballot(mask[i] != 0);
  int lane = threadIdx.x & 63;
  if (lane == 0)       bits[i >> 5] = (u32)bal;
  else if (lane == 32) bits[i >> 5] = (u32)(bal >> 32);
}

// ---------------- GEMM: C[8192][512] = A[8192][512] * Bt[512][512]^T + bias ----------------
// EPI 0: bf16 out, layout [B,H,S,D] (q,k)
// EPI 1: bf16 out, layout [B,H,D,S] (v transposed)
// EPI 2: fp32 out, row-major [8192][512] (final)
template <int EPI>
__global__ __launch_bounds__(256) void gemm_bt_kernel(
    const u16* __restrict__ A, const u16* __restrict__ Bt,
    const float* __restrict__ bias, void* __restrict__ outp) {
  __shared__ u16 As[128][40];
  __shared__ u16 Bs[128][40];
  const int t = threadIdx.x;
  const int lane = t & 63, wid = t >> 6;
  const int wr = wid >> 1, wc = wid & 1;
  const int l15 = lane & 15, l4 = lane >> 4;
  const int rm = blockIdx.x * 128, cn = blockIdx.y * 128;
  const int srow = t >> 2, scol = (t & 3) << 3;

  f32x4 acc[4][4] = {};

  for (int k0 = 0; k0 < DM_; k0 += 32) {
    __syncthreads();
    *(uint4*)(&As[srow][scol])      = *(const uint4*)(A + (size_t)(rm + srow) * DM_ + k0 + scol);
    *(uint4*)(&As[srow + 64][scol]) = *(const uint4*)(A + (size_t)(rm + srow + 64) * DM_ + k0 + scol);
    *(uint4*)(&Bs[srow][scol])      = *(const uint4*)(Bt + (size_t)(cn + srow) * DM_ + k0 + scol);
    *(uint4*)(&Bs[srow + 64][scol]) = *(const uint4*)(Bt + (size_t)(cn + srow + 64) * DM_ + k0 + scol);
    __syncthreads();
    bf16x8 af[4], bfr[4];
#pragma unroll
    for (int m = 0; m < 4; ++m)
      af[m] = *(const bf16x8*)(&As[wr * 64 + m * 16 + l15][l4 * 8]);
#pragma unroll
    for (int n = 0; n < 4; ++n)
      bfr[n] = *(const bf16x8*)(&Bs[wc * 64 + n * 16 + l15][l4 * 8]);
#pragma unroll
    for (int m = 0; m < 4; ++m)
#pragma unroll
      for (int n = 0; n < 4; ++n)
        acc[m][n] = __builtin_amdgcn_mfma_f32_16x16x32_bf16(af[m], bfr[n], acc[m][n], 0, 0, 0);
  }

#pragma unroll
  for (int m = 0; m < 4; ++m)
#pragma unroll
    for (int n = 0; n < 4; ++n) {
      int col = cn + wc * 64 + n * 16 + l15;
      float bv = bias[col];
#pragma unroll
      for (int r = 0; r < 4; ++r) {
        int row = rm + wr * 64 + m * 16 + l4 * 4 + r;
        float v = acc[m][n][r] + bv;
        if (EPI == 2) {
          ((float*)outp)[(size_t)row * DM_ + col] = v;
        } else {
          int b = row >> 11, s = row & 2047;
          int h = col >> 6, d = col & 63;
          u16* o = (u16*)outp;
          if (EPI == 0)
            o[(((size_t)(b * H_ + h)) * S_ + s) * D_ + d] = f2b(v);
          else
            o[(((size_t)(b * H_ + h)) * D_ + d) * S_ + s] = f2b(v);
        }
      }
    }
}

// ---------------- flash attention ----------------
// grid (S/64, H, B), 256 threads (4 waves x 16 q-rows). k-tiles of 32.
__global__ __launch_bounds__(256) void attn_kernel(
    const u16* __restrict__ qp, const u16* __restrict__ kp, const u16* __restrict__ vp,
    const u32* __restrict__ mbits, u16* __restrict__ ctx) {
  __shared__ u16 K_lds[32][72];   // [key][d]
  __shared__ u16 Vt_lds[64][40];  // [d][key]
  __shared__ u16 P_lds[4][16][40];// per-wave [q][key]
  const int t = threadIdx.x, lane = t & 63, w = t >> 6;
  const int l15 = lane & 15, l4 = lane >> 4;
  const int qt = blockIdx.x, h = blockIdx.y, b = blockIdx.z;
  const size_t head_off  = ((size_t)(b * H_ + h)) * S_ * D_;
  const size_t headT_off = ((size_t)(b * H_ + h)) * D_ * S_;

  const int qrow_frag = qt * 64 + w * 16 + l15;
  bf16x8 aq0 = *(const bf16x8*)(qp + head_off + (size_t)qrow_frag * D_ + l4 * 8);
  bf16x8 aq1 = *(const bf16x8*)(qp + head_off + (size_t)qrow_frag * D_ + 32 + l4 * 8);

  f32x4 acc[4] = {};
  float mrow[4], lrow[4];
#pragma unroll
  for (int r = 0; r < 4; ++r) { mrow[r] = -INFINITY; lrow[r] = 0.f; }
  const int qrow_d = qt * 64 + w * 16 + l4 * 4;

  const int krow = t >> 3, kcol = (t & 7) << 3;
  const int vrow = t >> 2, vcol = (t & 3) << 3;

  for (int kt = 0; kt < S_ / 32; ++kt) {
    __syncthreads();
    *(uint4*)(&K_lds[krow][kcol])  = *(const uint4*)(kp + head_off + (size_t)(kt * 32 + krow) * D_ + kcol);
    *(uint4*)(&Vt_lds[vrow][vcol]) = *(const uint4*)(vp + headT_off + (size_t)vrow * S_ + kt * 32 + vcol);
    __syncthreads();

    u32 mw[4];
#pragma unroll
    for (int r = 0; r < 4; ++r)
      mw[r] = mbits[((size_t)b * S_ + (qrow_d + r)) * (S_ / 32) + kt];

    f32x4 s0 = {}, s1 = {};
    bf16x8 bk;
    bk = *(const bf16x8*)(&K_lds[l15][l4 * 8]);
    s0 = __builtin_amdgcn_mfma_f32_16x16x32_bf16(aq0, bk, s0, 0, 0, 0);
    bk = *(const bf16x8*)(&K_lds[l15][32 + l4 * 8]);
    s0 = __builtin_amdgcn_mfma_f32_16x16x32_bf16(aq1, bk, s0, 0, 0, 0);
    bk = *(const bf16x8*)(&K_lds[16 + l15][l4 * 8]);
    s1 = __builtin_amdgcn_mfma_f32_16x16x32_bf16(aq0, bk, s1, 0, 0, 0);
    bk = *(const bf16x8*)(&K_lds[16 + l15][32 + l4 * 8]);
    s1 = __builtin_amdgcn_mfma_f32_16x16x32_bf16(aq1, bk, s1, 0, 0, 0);

    float p0[4], p1[4], sc[4];
#pragma unroll
    for (int r = 0; r < 4; ++r) {
      float v0 = ((mw[r] >> l15) & 1u)        ? s0[r] * 0.125f : NEG_INF_F;
      float v1 = ((mw[r] >> (16 + l15)) & 1u) ? s1[r] * 0.125f : NEG_INF_F;
      float cand = fmaxf(v0, v1);
      cand = fmaxf(cand, __shfl_xor(cand, 1, 16));
      cand = fmaxf(cand, __shfl_xor(cand, 2, 16));
      cand = fmaxf(cand, __shfl_xor(cand, 4, 16));
      cand = fmaxf(cand, __shfl_xor(cand, 8, 16));
      float mnew = fmaxf(mrow[r], cand);
      float scale = __expf(mrow[r] - mnew);
      float e0 = __expf(v0 - mnew), e1 = __expf(v1 - mnew);
      float rs = e0 + e1;
      rs += __shfl_xor(rs, 1, 16);
      rs += __shfl_xor(rs, 2, 16);
      rs += __shfl_xor(rs, 4, 16);
      rs += __shfl_xor(rs, 8, 16);
      lrow[r] = lrow[r] * scale + rs;
      mrow[r] = mnew;
      p0[r] = e0; p1[r] = e1; sc[r] = scale;
    }
#pragma unroll
    for (int n = 0; n < 4; ++n)
#pragma unroll
      for (int r = 0; r < 4; ++r) acc[n][r] *= sc[r];

#pragma unroll
    for (int r = 0; r < 4; ++r) {
      P_lds[w][l4 * 4 + r][l15]      = f2b(p0[r]);
      P_lds[w][l4 * 4 + r][16 + l15] = f2b(p1[r]);
    }
    __syncthreads();

    bf16x8 ap = *(const bf16x8*)(&P_lds[w][l15][l4 * 8]);
#pragma unroll
    for (int n = 0; n < 4; ++n) {
      bf16x8 bv = *(const bf16x8*)(&Vt_lds[n * 16 + l15][l4 * 8]);
      acc[n] = __builtin_amdgcn_mfma_f32_16x16x32_bf16(ap, bv, acc[n], 0, 0, 0);
    }
  }

  float inv[4];
#pragma unroll
  for (int r = 0; r < 4; ++r) inv[r] = 1.0f / lrow[r];
#pragma unroll
  for (int n = 0; n < 4; ++n)
#pragma unroll
    for (int r = 0; r < 4; ++r) {
      int qrow = qrow_d + r;
      int dcol = n * 16 + l15;
      ctx[((size_t)(b * S_) + qrow) * DM_ + h * D_ + dcol] = f2b(acc[n][r] * inv[r]);
    }
}

extern "C" void kernel_launch(void* const* d_in, const int* in_sizes, int n_in,
                              void* d_out, int out_size, void* d_ws, size_t ws_size,
                              hipStream_t stream) {
  const float* Q  = (const float*)d_in[0];
  const float* K  = (const float*)d_in[1];
  const float* V  = (const float*)d_in[2];
  const int* mask = (const int*)d_in[3];
  const float* Wq = (const float*)d_in[4];
  const float* bq = (const float*)d_in[5];
  const float* Wk = (const float*)d_in[6];
  const float* bk = (const float*)d_in[7];
  const float* Wv = (const float*)d_in[8];
  const float* bv = (const float*)d_in[9];
  const float* Wo = (const float*)d_in[10];
  const float* bo = (const float*)d_in[11];

  char* ws = (char*)d_ws;
  size_t off = 0;
  auto alloc = [&](size_t bytes) -> void* {
    void* p = ws + off;
    off += (bytes + 255) & ~(size_t)255;
    return p;
  };
  const size_t act_b = (size_t)B_ * S_ * DM_ * 2;  // 8 MB bf16 activations
  u16* Qb  = (u16*)alloc(act_b);
  u16* Kb  = (u16*)alloc(act_b);
  u16* Vb  = (u16*)alloc(act_b);
  u16* Wtq = (u16*)alloc((size_t)DM_ * DM_ * 2);
  u16* Wtk = (u16*)alloc((size_t)DM_ * DM_ * 2);
  u16* Wtv = (u16*)alloc((size_t)DM_ * DM_ * 2);
  u16* Wto = (u16*)alloc((size_t)DM_ * DM_ * 2);
  u32* mbits = (u32*)alloc((size_t)B_ * S_ * (S_ / 32) * 4);
  u16* qp  = (u16*)alloc(act_b);
  u16* kp  = (u16*)alloc(act_b);
  u16* vp  = (u16*)alloc(act_b);
  u16* ctx = (u16*)alloc(act_b);

  const int n4 = B_ * S_ * DM_ / 4;
  cast_f32_bf16_kernel<<<(n4 + 255) / 256, 256, 0, stream>>>(Q, Qb, n4);
  cast_f32_bf16_kernel<<<(n4 + 255) / 256, 256, 0, stream>>>(K, Kb, n4);
  cast_f32_bf16_kernel<<<(n4 + 255) / 256, 256, 0, stream>>>(V, Vb, n4);

  const int nw = DM_ * DM_;
  transpose_cast_w_kernel<<<nw / 256, 256, 0, stream>>>(Wq, Wtq);
  transpose_cast_w_kernel<<<nw / 256, 256, 0, stream>>>(Wk, Wtk);
  transpose_cast_w_kernel<<<nw / 256, 256, 0, stream>>>(Wv, Wtv);
  transpose_cast_w_kernel<<<nw / 256, 256, 0, stream>>>(Wo, Wto);

  pack_mask_kernel<<<(B_ * S_ * S_) / 256, 256, 0, stream>>>(mask, mbits);

  dim3 gg(8192 / 128, DM_ / 128);
  gemm_bt_kernel<0><<<gg, 256, 0, stream>>>(Qb, Wtq, bq, qp);
  gemm_bt_kernel<0><<<gg, 256, 0, stream>>>(Kb, Wtk, bk, kp);
  gemm_bt_kernel<1><<<gg, 256, 0, stream>>>(Vb, Wtv, bv, vp);

  dim3 ga(S_ / 64, H_, B_);
  attn_kernel<<<ga, 256, 0, stream>>>(qp, kp, vp, mbits, ctx);

  gemm_bt_kernel<2><<<gg, 256, 0, stream>>>(ctx, Wto, bo, (void*)d_out);
}

// Round 2
// 185.694 us; speedup vs baseline: 1.5519x; 1.5519x over previous
//
#include <hip/hip_runtime.h>
#include <hip/hip_bf16.h>
#include <stdint.h>

typedef unsigned short u16;
typedef unsigned int u32;
typedef unsigned long long u64;
using bf16x8 = __attribute__((ext_vector_type(8))) __bf16;
using f32x4  = __attribute__((ext_vector_type(4))) float;
using f32x16 = __attribute__((ext_vector_type(16))) float;

static constexpr int B_ = 4, H_ = 8, S_ = 2048, D_ = 64, DM_ = 512;
#define NEG_INF_F (-1000000000.0f)

__device__ __forceinline__ u16 f2b(float f) {
  u32 u = __float_as_uint(f);
  u = (u + 0x7FFFu + ((u >> 16) & 1u)) >> 16;
  return (u16)u;
}

__device__ __forceinline__ u32 cvtpk_bf16(float a, float b) {
  u32 r;
  asm("v_cvt_pk_bf16_f32 %0, %1, %2" : "=v"(r) : "v"(a), "v"(b));
  return r;
}
// new_a = {a.row0 | b.row0}; new_b = {a.row1 | b.row1}
__device__ __forceinline__ void plswap(u32& a, u32& b) {
  asm("v_permlane32_swap_b32 %0, %1" : "+v"(a), "+v"(b));
}
__device__ __forceinline__ void gload16(const void* g, void* lds) {
  __builtin_amdgcn_global_load_lds(
      (const __attribute__((address_space(1))) u32*)g,
      (__attribute__((address_space(3))) u32*)lds, 16, 0, 0);
}

// ---------------- cast fp32 -> bf16 (vectorized) ----------------
__global__ void cast_f32_bf16_kernel(const float* __restrict__ in, u16* __restrict__ out, int n4) {
  int i = blockIdx.x * blockDim.x + threadIdx.x;
  if (i >= n4) return;
  float4 v = reinterpret_cast<const float4*>(in)[i];
  ushort4 o;
  o.x = f2b(v.x); o.y = f2b(v.y); o.z = f2b(v.z); o.w = f2b(v.w);
  reinterpret_cast<ushort4*>(out)[i] = o;
}

// ---------------- W (K x N) -> Wt bf16 (N x K) ----------------
__global__ void transpose_cast_w_kernel(const float* __restrict__ W, u16* __restrict__ Wt) {
  int i = blockIdx.x * blockDim.x + threadIdx.x;
  int n = i >> 9, k = i & 511;
  Wt[i] = f2b(W[k * DM_ + n]);
}

// ---------------- mask int32 -> bitmask ----------------
__global__ void pack_mask_kernel(const int* __restrict__ mask, u32* __restrict__ bits) {
  int i = blockIdx.x * blockDim.x + threadIdx.x;
  unsigned long long bal = __ballot(mask[i] != 0);
  int lane = threadIdx.x & 63;
  if (lane == 0)       bits[i >> 5] = (u32)bal;
  else if (lane == 32) bits[i >> 5] = (u32)(bal >> 32);
}

// ---------------- GEMM: C[8192][512] = A[8192][512] * Bt[512][512]^T + bias, *scale ----------
// EPI 0: bf16 out, layout [B,H,S,D] (q,k)
// EPI 1: bf16 out, layout [B,H,D,S] (v transposed)
// EPI 2: fp32 out, row-major [8192][512] (final)
template <int EPI>
__global__ __launch_bounds__(256) void gemm_bt_kernel(
    const u16* __restrict__ A, const u16* __restrict__ Bt,
    const float* __restrict__ bias, void* __restrict__ outp, float scale) {
  __shared__ u16 As[128][40];
  __shared__ u16 Bs[128][40];
  const int t = threadIdx.x;
  const int lane = t & 63, wid = t >> 6;
  const int wr = wid >> 1, wc = wid & 1;
  const int l15 = lane & 15, l4 = lane >> 4;
  const int rm = blockIdx.x * 128, cn = blockIdx.y * 128;
  const int srow = t >> 2, scol = (t & 3) << 3;

  f32x4 acc[4][4] = {};

  for (int k0 = 0; k0 < DM_; k0 += 32) {
    __syncthreads();
    *(uint4*)(&As[srow][scol])      = *(const uint4*)(A + (size_t)(rm + srow) * DM_ + k0 + scol);
    *(uint4*)(&As[srow + 64][scol]) = *(const uint4*)(A + (size_t)(rm + srow + 64) * DM_ + k0 + scol);
    *(uint4*)(&Bs[srow][scol])      = *(const uint4*)(Bt + (size_t)(cn + srow) * DM_ + k0 + scol);
    *(uint4*)(&Bs[srow + 64][scol]) = *(const uint4*)(Bt + (size_t)(cn + srow + 64) * DM_ + k0 + scol);
    __syncthreads();
    bf16x8 af[4], bfr[4];
#pragma unroll
    for (int m = 0; m < 4; ++m)
      af[m] = *(const bf16x8*)(&As[wr * 64 + m * 16 + l15][l4 * 8]);
#pragma unroll
    for (int n = 0; n < 4; ++n)
      bfr[n] = *(const bf16x8*)(&Bs[wc * 64 + n * 16 + l15][l4 * 8]);
#pragma unroll
    for (int m = 0; m < 4; ++m)
#pragma unroll
      for (int n = 0; n < 4; ++n)
        acc[m][n] = __builtin_amdgcn_mfma_f32_16x16x32_bf16(af[m], bfr[n], acc[m][n], 0, 0, 0);
  }

#pragma unroll
  for (int m = 0; m < 4; ++m)
#pragma unroll
    for (int n = 0; n < 4; ++n) {
      int col = cn + wc * 64 + n * 16 + l15;
      float bv = bias[col];
#pragma unroll
      for (int r = 0; r < 4; ++r) {
        int row = rm + wr * 64 + m * 16 + l4 * 4 + r;
        float v = (acc[m][n][r] + bv) * scale;
        if (EPI == 2) {
          ((float*)outp)[(size_t)row * DM_ + col] = v;
        } else {
          int b = row >> 11, s = row & 2047;
          int h = col >> 6, d = col & 63;
          u16* o = (u16*)outp;
          if (EPI == 0)
            o[(((size_t)(b * H_ + h)) * S_ + s) * D_ + d] = f2b(v);
          else
            o[(((size_t)(b * H_ + h)) * D_ + d) * S_ + s] = f2b(v);
        }
      }
    }
}

// ---------------- flash attention, swapped-QK^T 32x32 structure ----------------
// grid (S/128, H, B), 256 threads = 4 waves x 32 q-rows. KV tiles of 64, double-buffered.
__global__ __launch_bounds__(256) void attn_kernel(
    const u16* __restrict__ qp, const u16* __restrict__ kp, const u16* __restrict__ vp,
    const u64* __restrict__ mbits, u16* __restrict__ ctx) {
  __shared__ __align__(16) u16 Kl[2][64][64];  // [buf][key][d], XOR-swizzled
  __shared__ __align__(16) u16 Vl[2][64][64];  // [buf][d][key], XOR-swizzled
  const int t = threadIdx.x, lane = t & 63, w = t >> 6;
  const int l31 = lane & 31, hi = lane >> 5;
  const int h = blockIdx.y, b = blockIdx.z;
  const size_t head  = ((size_t)(b * H_ + h)) * S_ * D_;
  const size_t headT = ((size_t)(b * H_ + h)) * D_ * S_;
  const int q0 = blockIdx.x * 128 + w * 32;
  const int q  = q0 + l31;

  // Q fragments, hoisted (B-operand: col q = lane&31, k = ks*16 + hi*8 + j)
  bf16x8 qf[4];
  {
    const u16* qrow = qp + head + (size_t)q * D_;
#pragma unroll
    for (int ks = 0; ks < 4; ++ks) qf[ks] = *(const bf16x8*)(qrow + ks * 16 + hi * 8);
  }

  // LDS read addressing: byte = row*128 + ((col) ^ ((row&7)<<4)); rows are l31 / 32+l31
  const int kxor = (l31 & 7) << 4;
  const int rbase0 = l31 * 128, rbase1 = (32 + l31) * 128;
  int colx[4];
#pragma unroll
  for (int s = 0; s < 4; ++s) colx[s] = ((s * 32 + hi * 16) ^ kxor);

  // staging: lane covers (row = chunk*8 + lane>>3, col16 = lane&7); source col pre-swizzled
  const int srow = lane >> 3;
  const int scol = ((lane & 7) ^ srow) << 3;  // elements
  const int c0 = w, c1 = w + 4;
  const u16* ksrc0 = kp + head + (size_t)(c0 * 8 + srow) * D_ + scol;
  const u16* ksrc1 = kp + head + (size_t)(c1 * 8 + srow) * D_ + scol;
  const u16* vsrc0 = vp + headT + (size_t)(c0 * 8 + srow) * S_ + scol;
  const u16* vsrc1 = vp + headT + (size_t)(c1 * 8 + srow) * S_ + scol;

  f32x16 accO0, accO1;
#pragma unroll
  for (int i = 0; i < 16; ++i) { accO0[i] = 0.f; accO1[i] = 0.f; }
  float mrow = -INFINITY, lrow = 0.f;

  const u64* mrowp = mbits + ((size_t)b * S_ + q) * (S_ / 64);

  auto stage = [&](int bufi, int kt) {
    char* kb = (char*)Kl + bufi * 8192;
    char* vb = (char*)Vl + bufi * 8192;
    gload16(ksrc0 + (size_t)kt * 4096, kb + c0 * 1024);
    gload16(ksrc1 + (size_t)kt * 4096, kb + c1 * 1024);
    gload16(vsrc0 + kt * 64, vb + c0 * 1024);
    gload16(vsrc1 + kt * 64, vb + c1 * 1024);
  };

  stage(0, 0);
  __syncthreads();
  int buf = 0;

  for (int kt = 0; kt < S_ / 64; ++kt) {
    if (kt < S_ / 64 - 1) stage(buf ^ 1, kt + 1);
    u64 mw = mrowp[kt] >> (hi * 4);
    const u32 mlo = (u32)mw, mhi = (u32)(mw >> 32);

    const char* kb = (const char*)Kl + buf * 8192;
    const char* vb = (const char*)Vl + buf * 8192;

    // QK^T swapped: S^T[key][q], lane holds one q-row across key-regs
    f32x16 s0, s1;
#pragma unroll
    for (int i = 0; i < 16; ++i) { s0[i] = 0.f; s1[i] = 0.f; }
#pragma unroll
    for (int ks = 0; ks < 4; ++ks) {
      bf16x8 kf = *(const bf16x8*)(kb + rbase0 + colx[ks]);
      s0 = __builtin_amdgcn_mfma_f32_32x32x16_bf16(kf, qf[ks], s0, 0, 0, 0);
    }
#pragma unroll
    for (int ks = 0; ks < 4; ++ks) {
      bf16x8 kf = *(const bf16x8*)(kb + rbase1 + colx[ks]);
      s1 = __builtin_amdgcn_mfma_f32_32x32x16_bf16(kf, qf[ks], s1, 0, 0, 0);
    }

    // mask (reg r of set c <-> key c*32 + (r&3)+8*(r>>2)+4*hi; mw pre-shifted by 4*hi)
    float sc[32];
    float tm[4] = {NEG_INF_F, NEG_INF_F, NEG_INF_F, NEG_INF_F};
#pragma unroll
    for (int c = 0; c < 2; ++c)
#pragma unroll
      for (int r = 0; r < 16; ++r) {
        const int kbit = c * 32 + (r & 3) + 8 * (r >> 2);
        const u32 wsel = (kbit < 32) ? mlo : mhi;
        float v = ((wsel >> (kbit & 31)) & 1u) ? (c ? s1[r] : s0[r]) : NEG_INF_F;
        sc[c * 16 + r] = v;
        tm[r & 3] = fmaxf(tm[r & 3], v);
      }
    float tmax = fmaxf(fmaxf(tm[0], tm[1]), fmaxf(tm[2], tm[3]));
    tmax = fmaxf(tmax, __shfl_xor(tmax, 32));

    // defer-max (T13, THR=8)
    if (__any(tmax > mrow + 8.f)) {
      float mnew = fmaxf(mrow, tmax);
      float scl = __expf(mrow - mnew);
      mrow = mnew;
      lrow *= scl;
#pragma unroll
      for (int i = 0; i < 16; ++i) { accO0[i] *= scl; accO1[i] *= scl; }
    }

    float rs[4] = {0.f, 0.f, 0.f, 0.f};
#pragma unroll
    for (int i = 0; i < 32; ++i) {
      float e = __expf(sc[i] - mrow);
      sc[i] = e;
      rs[i & 3] += e;
    }
    float rsum = (rs[0] + rs[1]) + (rs[2] + rs[3]);
    rsum += __shfl_xor(rsum, 32);
    lrow += rsum;

    // P -> MFMA A-fragments in-register (T12): cvt_pk + permlane32_swap
#pragma unroll
    for (int c = 0; c < 2; ++c) {
      u32 pw[8];
#pragma unroll
      for (int j = 0; j < 8; ++j)
        pw[j] = cvtpk_bf16(sc[c * 16 + 2 * j], sc[c * 16 + 2 * j + 1]);
      plswap(pw[0], pw[2]); plswap(pw[1], pw[3]);
      plswap(pw[4], pw[6]); plswap(pw[5], pw[7]);
#pragma unroll
      for (int s = 0; s < 2; ++s) {
        union { u32 wds[4]; bf16x8 v; } pa;
        pa.wds[0] = pw[s * 4 + 0]; pa.wds[1] = pw[s * 4 + 1];
        pa.wds[2] = pw[s * 4 + 2]; pa.wds[3] = pw[s * 4 + 3];
        const int slice = c * 2 + s;
        bf16x8 vf0 = *(const bf16x8*)(vb + rbase0 + colx[slice]);
        accO0 = __builtin_amdgcn_mfma_f32_32x32x16_bf16(pa.v, vf0, accO0, 0, 0, 0);
        bf16x8 vf1 = *(const bf16x8*)(vb + rbase1 + colx[slice]);
        accO1 = __builtin_amdgcn_mfma_f32_32x32x16_bf16(pa.v, vf1, accO1, 0, 0, 0);
      }
    }
    __syncthreads();
    buf ^= 1;
  }

  // epilogue: O[q][d] with row q = (r&3)+8*(r>>2)+4*hi, col d = set*32 + l31
  float inv = 1.0f / lrow;
  float invr[16];
#pragma unroll
  for (int r = 0; r < 16; ++r) invr[r] = __shfl(inv, (r & 3) + 8 * (r >> 2) + 4 * hi);

  const int colA = h * 64 + l31, colB = h * 64 + 32 + l31;
#pragma unroll
  for (int r = 0; r < 16; ++r) {
    const int row = q0 + (r & 3) + 8 * (r >> 2) + 4 * hi;
    u16* o = ctx + ((size_t)(b * S_) + row) * DM_;
    o[colA] = f2b(accO0[r] * invr[r]);
    o[colB] = f2b(accO1[r] * invr[r]);
  }
}

extern "C" void kernel_launch(void* const* d_in, const int* in_sizes, int n_in,
                              void* d_out, int out_size, void* d_ws, size_t ws_size,
                              hipStream_t stream) {
  const float* Q  = (const float*)d_in[0];
  const float* K  = (const float*)d_in[1];
  const float* V  = (const float*)d_in[2];
  const int* mask = (const int*)d_in[3];
  const float* Wq = (const float*)d_in[4];
  const float* bq = (const float*)d_in[5];
  const float* Wk = (const float*)d_in[6];
  const float* bk = (const float*)d_in[7];
  const float* Wv = (const float*)d_in[8];
  const float* bv = (const float*)d_in[9];
  const float* Wo = (const float*)d_in[10];
  const float* bo = (const float*)d_in[11];

  char* ws = (char*)d_ws;
  size_t off = 0;
  auto alloc = [&](size_t bytes) -> void* {
    void* p = ws + off;
    off += (bytes + 255) & ~(size_t)255;
    return p;
  };
  const size_t act_b = (size_t)B_ * S_ * DM_ * 2;
  u16* Qb  = (u16*)alloc(act_b);
  u16* Kb  = (u16*)alloc(act_b);
  u16* Vb  = (u16*)alloc(act_b);
  u16* Wtq = (u16*)alloc((size_t)DM_ * DM_ * 2);
  u16* Wtk = (u16*)alloc((size_t)DM_ * DM_ * 2);
  u16* Wtv = (u16*)alloc((size_t)DM_ * DM_ * 2);
  u16* Wto = (u16*)alloc((size_t)DM_ * DM_ * 2);
  u32* mbits = (u32*)alloc((size_t)B_ * S_ * (S_ / 32) * 4);
  u16* qp  = (u16*)alloc(act_b);
  u16* kp  = (u16*)alloc(act_b);
  u16* vp  = (u16*)alloc(act_b);
  u16* ctx = (u16*)alloc(act_b);

  const int n4 = B_ * S_ * DM_ / 4;
  cast_f32_bf16_kernel<<<(n4 + 255) / 256, 256, 0, stream>>>(Q, Qb, n4);
  cast_f32_bf16_kernel<<<(n4 + 255) / 256, 256, 0, stream>>>(K, Kb, n4);
  cast_f32_bf16_kernel<<<(n4 + 255) / 256, 256, 0, stream>>>(V, Vb, n4);

  const int nw = DM_ * DM_;
  transpose_cast_w_kernel<<<nw / 256, 256, 0, stream>>>(Wq, Wtq);
  transpose_cast_w_kernel<<<nw / 256, 256, 0, stream>>>(Wk, Wtk);
  transpose_cast_w_kernel<<<nw / 256, 256, 0, stream>>>(Wv, Wtv);
  transpose_cast_w_kernel<<<nw / 256, 256, 0, stream>>>(Wo, Wto);

  pack_mask_kernel<<<(B_ * S_ * S_) / 256, 256, 0, stream>>>(mask, mbits);

  dim3 gg(8192 / 128, DM_ / 128);
  gemm_bt_kernel<0><<<gg, 256, 0, stream>>>(Qb, Wtq, bq, qp, 0.125f);  // 1/sqrt(64) folded into q
  gemm_bt_kernel<0><<<gg, 256, 0, stream>>>(Kb, Wtk, bk, kp, 1.0f);
  gemm_bt_kernel<1><<<gg, 256, 0, stream>>>(Vb, Wtv, bv, vp, 1.0f);

  dim3 ga(S_ / 128, H_, B_);
  attn_kernel<<<ga, 256, 0, stream>>>(qp, kp, vp, (const u64*)mbits, ctx);

  gemm_bt_kernel<2><<<gg, 256, 0, stream>>>(ctx, Wto, bo, (void*)d_out, 1.0f);
}

// Round 3
// 150.962 us; speedup vs baseline: 1.9090x; 1.2301x over previous
//
#include <hip/hip_runtime.h>
#include <hip/hip_bf16.h>
#include <stdint.h>

typedef unsigned short u16;
typedef unsigned int u32;
typedef unsigned long long u64;
using bf16x8 = __attribute__((ext_vector_type(8))) __bf16;
using f32x4  = __attribute__((ext_vector_type(4))) float;
using f32x16 = __attribute__((ext_vector_type(16))) float;

static constexpr int B_ = 4, H_ = 8, S_ = 2048, D_ = 64, DM_ = 512;
// 0.125 (1/sqrt(64)) * log2(e): folds softmax exp->exp2 into q projection
#define QSCALE 0.1803368801111601f

__device__ __forceinline__ u16 f2b(float f) {
  u32 u = __float_as_uint(f);
  u = (u + 0x7FFFu + ((u >> 16) & 1u)) >> 16;
  return (u16)u;
}

__device__ __forceinline__ u32 cvtpk_bf16(float a, float b) {
  u32 r;
  asm("v_cvt_pk_bf16_f32 %0, %1, %2" : "=v"(r) : "v"(a), "v"(b));
  return r;
}
__device__ __forceinline__ void plswap(u32& a, u32& b) {
  asm("v_permlane32_swap_b32 %0, %1" : "+v"(a), "+v"(b));
}
__device__ __forceinline__ void gload16(const void* g, void* lds) {
  __builtin_amdgcn_global_load_lds(
      (const __attribute__((address_space(1))) u32*)g,
      (__attribute__((address_space(3))) u32*)lds, 16, 0, 0);
}
#if __has_builtin(__builtin_amdgcn_exp2f)
__device__ __forceinline__ float exp2fast(float x) { return __builtin_amdgcn_exp2f(x); }
#else
__device__ __forceinline__ float exp2fast(float x) {
  float r;
  asm("v_exp_f32 %0, %1" : "=v"(r) : "v"(x));
  return r;
}
#endif

// ---------------- weight prep: W fp32 [k][n] -> Wt bf16 [n][k], 4 weights ----------------
__global__ __launch_bounds__(256) void prep_w_kernel(
    const float* __restrict__ Wq, const float* __restrict__ Wk,
    const float* __restrict__ Wv, const float* __restrict__ Wo,
    u16* __restrict__ Wtq, u16* __restrict__ Wtk, u16* __restrict__ Wtv, u16* __restrict__ Wto) {
  __shared__ float tile[32][33];
  const int z = blockIdx.z;
  const float* W = z == 0 ? Wq : z == 1 ? Wk : z == 2 ? Wv : Wo;
  u16* Wt       = z == 0 ? Wtq : z == 1 ? Wtk : z == 2 ? Wtv : Wto;
  const int k0 = blockIdx.x * 32, n0 = blockIdx.y * 32;
  const int t = threadIdx.x;
  {
    const int kl = t >> 3, nl4 = (t & 7) * 4;
    float4 v = *(const float4*)(W + (size_t)(k0 + kl) * DM_ + n0 + nl4);
    tile[kl][nl4 + 0] = v.x; tile[kl][nl4 + 1] = v.y;
    tile[kl][nl4 + 2] = v.z; tile[kl][nl4 + 3] = v.w;
  }
  __syncthreads();
  {
    const int nl = t >> 3, kl4 = (t & 7) * 4;
    ushort4 o;
    o.x = f2b(tile[kl4 + 0][nl]); o.y = f2b(tile[kl4 + 1][nl]);
    o.z = f2b(tile[kl4 + 2][nl]); o.w = f2b(tile[kl4 + 3][nl]);
    *(ushort4*)(Wt + (size_t)(n0 + nl) * DM_ + k0 + kl4) = o;
  }
}

// ---------------- mask int32 -> bitmask ----------------
__global__ void pack_mask_kernel(const int* __restrict__ mask, u32* __restrict__ bits) {
  int i = blockIdx.x * blockDim.x + threadIdx.x;
  unsigned long long bal = __ballot(mask[i] != 0);
  int lane = threadIdx.x & 63;
  if (lane == 0)       bits[i >> 5] = (u32)bal;
  else if (lane == 32) bits[i >> 5] = (u32)(bal >> 32);
}

// ---------------- fused QKV projection GEMM ----------------
// grid (4 col-tiles, 64 m-panels, 3), 128x128 tile, A fp32 converted in staging.
// z=0: Q -> qp [B,H,S,D] * QSCALE ; z=1: K -> kp [B,H,S,D] ; z=2: V -> vp [B,H,D,S]
__global__ __launch_bounds__(256) void gemm_qkv_kernel(
    const float* __restrict__ Qf, const float* __restrict__ Kf, const float* __restrict__ Vf,
    const u16* __restrict__ Wtq, const u16* __restrict__ Wtk, const u16* __restrict__ Wtv,
    const float* __restrict__ bq, const float* __restrict__ bk, const float* __restrict__ bv,
    u16* __restrict__ qp, u16* __restrict__ kp, u16* __restrict__ vp) {
  __shared__ u16 As[128][40];
  __shared__ u16 Bs[128][40];
  const int z = blockIdx.z;
  const float* A    = z == 0 ? Qf : z == 1 ? Kf : Vf;
  const u16* Bt     = z == 0 ? Wtq : z == 1 ? Wtk : Wtv;
  const float* bias = z == 0 ? bq : z == 1 ? bk : bv;
  u16* outp         = z == 0 ? qp : z == 1 ? kp : vp;
  const float scale = z == 0 ? QSCALE : 1.0f;

  const int t = threadIdx.x;
  const int lane = t & 63, wid = t >> 6;
  const int wr = wid >> 1, wc = wid & 1;
  const int l15 = lane & 15, l4 = lane >> 4;
  const int cn = blockIdx.x * 128, rm = blockIdx.y * 128;
  const int srow = t >> 2, scol = (t & 3) << 3;

  f32x4 acc[4][4] = {};

  for (int k0 = 0; k0 < DM_; k0 += 32) {
    __syncthreads();
    {
      const float* a0 = A + (size_t)(rm + srow) * DM_ + k0 + scol;
      float4 f0 = *(const float4*)a0, f1 = *(const float4*)(a0 + 4);
      uint4 u;
      u.x = cvtpk_bf16(f0.x, f0.y); u.y = cvtpk_bf16(f0.z, f0.w);
      u.z = cvtpk_bf16(f1.x, f1.y); u.w = cvtpk_bf16(f1.z, f1.w);
      *(uint4*)(&As[srow][scol]) = u;
      const float* a1 = A + (size_t)(rm + srow + 64) * DM_ + k0 + scol;
      float4 g0 = *(const float4*)a1, g1 = *(const float4*)(a1 + 4);
      uint4 w2;
      w2.x = cvtpk_bf16(g0.x, g0.y); w2.y = cvtpk_bf16(g0.z, g0.w);
      w2.z = cvtpk_bf16(g1.x, g1.y); w2.w = cvtpk_bf16(g1.z, g1.w);
      *(uint4*)(&As[srow + 64][scol]) = w2;
    }
    *(uint4*)(&Bs[srow][scol])      = *(const uint4*)(Bt + (size_t)(cn + srow) * DM_ + k0 + scol);
    *(uint4*)(&Bs[srow + 64][scol]) = *(const uint4*)(Bt + (size_t)(cn + srow + 64) * DM_ + k0 + scol);
    __syncthreads();
    bf16x8 af[4], bfr[4];
#pragma unroll
    for (int m = 0; m < 4; ++m)
      af[m] = *(const bf16x8*)(&As[wr * 64 + m * 16 + l15][l4 * 8]);
#pragma unroll
    for (int n = 0; n < 4; ++n)
      bfr[n] = *(const bf16x8*)(&Bs[wc * 64 + n * 16 + l15][l4 * 8]);
#pragma unroll
    for (int m = 0; m < 4; ++m)
#pragma unroll
      for (int n = 0; n < 4; ++n)
        acc[m][n] = __builtin_amdgcn_mfma_f32_16x16x32_bf16(af[m], bfr[n], acc[m][n], 0, 0, 0);
  }

#pragma unroll
  for (int m = 0; m < 4; ++m)
#pragma unroll
    for (int n = 0; n < 4; ++n) {
      int col = cn + wc * 64 + n * 16 + l15;
      float bv_ = bias[col];
#pragma unroll
      for (int r = 0; r < 4; ++r) {
        int row = rm + wr * 64 + m * 16 + l4 * 4 + r;
        float v = (acc[m][n][r] + bv_) * scale;
        int b = row >> 11, s = row & 2047;
        int h = col >> 6, d = col & 63;
        if (z < 2)
          outp[(((size_t)(b * H_ + h)) * S_ + s) * D_ + d] = f2b(v);
        else
          outp[(((size_t)(b * H_ + h)) * D_ + d) * S_ + s] = f2b(v);
      }
    }
}

// ---------------- output GEMM: out[8192][512] fp32 = ctx bf16 @ Wo^T + bo ----------------
// 64x128 tiles, grid (4 col-tiles, 128 m-panels)
__global__ __launch_bounds__(256) void gemm_out_kernel(
    const u16* __restrict__ A, const u16* __restrict__ Bt,
    const float* __restrict__ bias, float* __restrict__ outp) {
  __shared__ u16 As[64][40];
  __shared__ u16 Bs[128][40];
  const int t = threadIdx.x;
  const int lane = t & 63, w = t >> 6;
  const int l15 = lane & 15, l4 = lane >> 4;
  const int cn = blockIdx.x * 128, rm = blockIdx.y * 64;
  const int srow = t >> 2, scol = (t & 3) << 3;

  f32x4 acc[4][2] = {};

  for (int k0 = 0; k0 < DM_; k0 += 32) {
    __syncthreads();
    *(uint4*)(&As[srow][scol])      = *(const uint4*)(A + (size_t)(rm + srow) * DM_ + k0 + scol);
    *(uint4*)(&Bs[srow][scol])      = *(const uint4*)(Bt + (size_t)(cn + srow) * DM_ + k0 + scol);
    *(uint4*)(&Bs[srow + 64][scol]) = *(const uint4*)(Bt + (size_t)(cn + srow + 64) * DM_ + k0 + scol);
    __syncthreads();
    bf16x8 af[4], bfr[2];
#pragma unroll
    for (int m = 0; m < 4; ++m)
      af[m] = *(const bf16x8*)(&As[m * 16 + l15][l4 * 8]);
#pragma unroll
    for (int n = 0; n < 2; ++n)
      bfr[n] = *(const bf16x8*)(&Bs[w * 32 + n * 16 + l15][l4 * 8]);
#pragma unroll
    for (int m = 0; m < 4; ++m)
#pragma unroll
      for (int n = 0; n < 2; ++n)
        acc[m][n] = __builtin_amdgcn_mfma_f32_16x16x32_bf16(af[m], bfr[n], acc[m][n], 0, 0, 0);
  }

#pragma unroll
  for (int m = 0; m < 4; ++m)
#pragma unroll
    for (int n = 0; n < 2; ++n) {
      int col = cn + w * 32 + n * 16 + l15;
      float bv_ = bias[col];
#pragma unroll
      for (int r = 0; r < 4; ++r) {
        int row = rm + m * 16 + l4 * 4 + r;
        outp[(size_t)row * DM_ + col] = acc[m][n][r] + bv_;
      }
    }
}

// ---------------- flash attention, swapped-QK^T 32x32, no-max softmax ----------------
// 512 blocks (XCD-swizzled), 256 threads = 4 waves x 32 q-rows. KV tiles of 64, dbuf.
__global__ __launch_bounds__(256) void attn_kernel(
    const u16* __restrict__ qp, const u16* __restrict__ kp, const u16* __restrict__ vp,
    const u64* __restrict__ mbits, u16* __restrict__ ctx) {
  __shared__ __align__(16) u16 Kl[2][64][64];
  __shared__ __align__(16) u16 Vl[2][64][64];
  const int t = threadIdx.x, lane = t & 63, w = t >> 6;
  const int l31 = lane & 31, hi = lane >> 5;
  // XCD-aware remap: wgid%8 = XCD; give each XCD one head (all batches, all q-tiles)
  const int wgid = blockIdx.x + 16 * (blockIdx.y + 8 * blockIdx.z);
  const int xcd = wgid & 7, idx = wgid >> 3;
  const int h = xcd, b = idx >> 4, qt = idx & 15;
  const size_t head  = ((size_t)(b * H_ + h)) * S_ * D_;
  const size_t headT = ((size_t)(b * H_ + h)) * D_ * S_;
  const int q0 = qt * 128 + w * 32;
  const int q  = q0 + l31;

  bf16x8 qf[4];
  {
    const u16* qrow = qp + head + (size_t)q * D_;
#pragma unroll
    for (int ks = 0; ks < 4; ++ks) qf[ks] = *(const bf16x8*)(qrow + ks * 16 + hi * 8);
  }

  const int kxor = (l31 & 7) << 4;
  const int rbase0 = l31 * 128, rbase1 = (32 + l31) * 128;
  int colx[4];
#pragma unroll
  for (int s = 0; s < 4; ++s) colx[s] = ((s * 32 + hi * 16) ^ kxor);

  const int srow = lane >> 3;
  const int scol = ((lane & 7) ^ srow) << 3;
  const int c0 = w, c1 = w + 4;
  const u16* ksrc0 = kp + head + (size_t)(c0 * 8 + srow) * D_ + scol;
  const u16* ksrc1 = kp + head + (size_t)(c1 * 8 + srow) * D_ + scol;
  const u16* vsrc0 = vp + headT + (size_t)(c0 * 8 + srow) * S_ + scol;
  const u16* vsrc1 = vp + headT + (size_t)(c1 * 8 + srow) * S_ + scol;

  f32x16 accO0, accO1;
#pragma unroll
  for (int i = 0; i < 16; ++i) { accO0[i] = 0.f; accO1[i] = 0.f; }
  float lrow = 0.f;

  const u64* mrowp = mbits + ((size_t)b * S_ + q) * (S_ / 64);

  auto stage = [&](int bufi, int kt) {
    char* kb = (char*)Kl + bufi * 8192;
    char* vb = (char*)Vl + bufi * 8192;
    gload16(ksrc0 + (size_t)kt * 4096, kb + c0 * 1024);
    gload16(ksrc1 + (size_t)kt * 4096, kb + c1 * 1024);
    gload16(vsrc0 + kt * 64, vb + c0 * 1024);
    gload16(vsrc1 + kt * 64, vb + c1 * 1024);
  };

  stage(0, 0);
  __syncthreads();
  int buf = 0;

  for (int kt = 0; kt < S_ / 64; ++kt) {
    if (kt < S_ / 64 - 1) stage(buf ^ 1, kt + 1);
    u64 mw = mrowp[kt] >> (hi * 4);
    const u32 mlo = (u32)mw, mhi = (u32)(mw >> 32);

    const char* kb = (const char*)Kl + buf * 8192;
    const char* vb = (const char*)Vl + buf * 8192;

    f32x16 s0, s1;
#pragma unroll
    for (int i = 0; i < 16; ++i) { s0[i] = 0.f; s1[i] = 0.f; }
    __builtin_amdgcn_s_setprio(1);
#pragma unroll
    for (int ks = 0; ks < 4; ++ks) {
      bf16x8 kf = *(const bf16x8*)(kb + rbase0 + colx[ks]);
      s0 = __builtin_amdgcn_mfma_f32_32x32x16_bf16(kf, qf[ks], s0, 0, 0, 0);
    }
#pragma unroll
    for (int ks = 0; ks < 4; ++ks) {
      bf16x8 kf = *(const bf16x8*)(kb + rbase1 + colx[ks]);
      s1 = __builtin_amdgcn_mfma_f32_32x32x16_bf16(kf, qf[ks], s1, 0, 0, 0);
    }
    __builtin_amdgcn_s_setprio(0);

    // no-max softmax: e = mask ? exp2(s) : 0  (q pre-scaled by 0.125*log2e)
    float e[32];
    float rs[4] = {0.f, 0.f, 0.f, 0.f};
#pragma unroll
    for (int c = 0; c < 2; ++c)
#pragma unroll
      for (int r = 0; r < 16; ++r) {
        const int kbit = c * 32 + (r & 3) + 8 * (r >> 2);
        const u32 wsel = (kbit < 32) ? mlo : mhi;
        float ex = exp2fast(c ? s1[r] : s0[r]);
        ex = ((wsel >> (kbit & 31)) & 1u) ? ex : 0.f;
        e[c * 16 + r] = ex;
        rs[r & 3] += ex;
      }
    float rsum = (rs[0] + rs[1]) + (rs[2] + rs[3]);
    rsum += __shfl_xor(rsum, 32);
    lrow += rsum;

    // P -> MFMA A-fragments in-register: cvt_pk + permlane32_swap
#pragma unroll
    for (int c = 0; c < 2; ++c) {
      u32 pw[8];
#pragma unroll
      for (int j = 0; j < 8; ++j)
        pw[j] = cvtpk_bf16(e[c * 16 + 2 * j], e[c * 16 + 2 * j + 1]);
      plswap(pw[0], pw[2]); plswap(pw[1], pw[3]);
      plswap(pw[4], pw[6]); plswap(pw[5], pw[7]);
      __builtin_amdgcn_s_setprio(1);
#pragma unroll
      for (int s = 0; s < 2; ++s) {
        union { u32 wds[4]; bf16x8 v; } pa;
        pa.wds[0] = pw[s * 4 + 0]; pa.wds[1] = pw[s * 4 + 1];
        pa.wds[2] = pw[s * 4 + 2]; pa.wds[3] = pw[s * 4 + 3];
        const int slice = c * 2 + s;
        bf16x8 vf0 = *(const bf16x8*)(vb + rbase0 + colx[slice]);
        accO0 = __builtin_amdgcn_mfma_f32_32x32x16_bf16(pa.v, vf0, accO0, 0, 0, 0);
        bf16x8 vf1 = *(const bf16x8*)(vb + rbase1 + colx[slice]);
        accO1 = __builtin_amdgcn_mfma_f32_32x32x16_bf16(pa.v, vf1, accO1, 0, 0, 0);
      }
      __builtin_amdgcn_s_setprio(0);
    }
    __syncthreads();
    buf ^= 1;
  }

  float inv = 1.0f / lrow;
  float invr[16];
#pragma unroll
  for (int r = 0; r < 16; ++r) invr[r] = __shfl(inv, (r & 3) + 8 * (r >> 2) + 4 * hi);

  const int colA = h * 64 + l31, colB = h * 64 + 32 + l31;
#pragma unroll
  for (int r = 0; r < 16; ++r) {
    const int row = q0 + (r & 3) + 8 * (r >> 2) + 4 * hi;
    u16* o = ctx + ((size_t)(b * S_) + row) * DM_;
    o[colA] = f2b(accO0[r] * invr[r]);
    o[colB] = f2b(accO1[r] * invr[r]);
  }
}

extern "C" void kernel_launch(void* const* d_in, const int* in_sizes, int n_in,
                              void* d_out, int out_size, void* d_ws, size_t ws_size,
                              hipStream_t stream) {
  const float* Q  = (const float*)d_in[0];
  const float* K  = (const float*)d_in[1];
  const float* V  = (const float*)d_in[2];
  const int* mask = (const int*)d_in[3];
  const float* Wq = (const float*)d_in[4];
  const float* bq = (const float*)d_in[5];
  const float* Wk = (const float*)d_in[6];
  const float* bk = (const float*)d_in[7];
  const float* Wv = (const float*)d_in[8];
  const float* bv = (const float*)d_in[9];
  const float* Wo = (const float*)d_in[10];
  const float* bo = (const float*)d_in[11];

  char* ws = (char*)d_ws;
  size_t off = 0;
  auto alloc = [&](size_t bytes) -> void* {
    void* p = ws + off;
    off += (bytes + 255) & ~(size_t)255;
    return p;
  };
  const size_t act_b = (size_t)B_ * S_ * DM_ * 2;
  u16* Wtq = (u16*)alloc((size_t)DM_ * DM_ * 2);
  u16* Wtk = (u16*)alloc((size_t)DM_ * DM_ * 2);
  u16* Wtv = (u16*)alloc((size_t)DM_ * DM_ * 2);
  u16* Wto = (u16*)alloc((size_t)DM_ * DM_ * 2);
  u32* mbits = (u32*)alloc((size_t)B_ * S_ * (S_ / 32) * 4);
  u16* qp  = (u16*)alloc(act_b);
  u16* kp  = (u16*)alloc(act_b);
  u16* vp  = (u16*)alloc(act_b);
  u16* ctx = (u16*)alloc(act_b);

  prep_w_kernel<<<dim3(16, 16, 4), 256, 0, stream>>>(Wq, Wk, Wv, Wo, Wtq, Wtk, Wtv, Wto);
  pack_mask_kernel<<<(B_ * S_ * S_) / 256, 256, 0, stream>>>(mask, mbits);

  gemm_qkv_kernel<<<dim3(4, 64, 3), 256, 0, stream>>>(
      Q, K, V, Wtq, Wtk, Wtv, bq, bk, bv, qp, kp, vp);

  attn_kernel<<<dim3(16, 8, 4), 256, 0, stream>>>(qp, kp, vp, (const u64*)mbits, ctx);

  gemm_out_kernel<<<dim3(4, 128), 256, 0, stream>>>(ctx, Wto, bo, (float*)d_out);
}